// Round 3
// baseline (549.444 us; speedup 1.0000x reference)
//
#include <hip/hip_runtime.h>

// Involution: out[b, g*64+c, ho, wo] = sum_{kh,kw} xp[b, g*64+c, ho+kh, wo+kw] * W[b,g,kh,kw,ho,wo]
// B=8, C=512, G=8, cpg=64, H=W=Ho=Wo=64, K=7, PAD=3. fp32.
//
// R7: register-free pipelining. R5/R6 proved the allocator pins 64 VGPR and
// spills any pipeline state above it (FETCH 124->379 MB). So move the
// pipeline into hardware:
//   - x staging via global_load_lds DMA (no VGPR round trip, no staging VALU)
//   - LDS double-buffer (2x32256B); chunk cc+1's DMA issued mid-compute of
//     chunk cc (after KH_STEP(2)) -> ~2 kh-steps (~800cy) of FMA cover.
//   - raw s_barrier + manual vmcnt (NOT __syncthreads: that drains vmcnt(0)
//     and would kill the in-flight DMA). FIFO vmcnt: each kh-step's
//     compiler-counted weight wait retires the older DMA entries before the
//     end-of-chunk barrier -> one barrier per chunk is sufficient.
//   - pad slots zeroed ONCE (sval mask identical every chunk; DMA is
//     exec-masked and never writes them).
//   - weight taps double-buffered wka/wkb (28 regs) - affordable with q[]
//     gone: live ~= wk 28 + acc 16 + addr/temps ~20 = ~64.
// Occupancy: 2 blocks/CU (LDS 64.5KB) = 8 waves/CU - fine, hiding is explicit.

#define BB 8
#define CC 512
#define GG 8
#define CPG 64
#define HH 64
#define WW 64
#define HW (HH * WW)
#define KK 7
#define PAD 3

#define TILE_ROWS 8
#define CSPLIT 2
#define NCHUNK 4                         // channel chunks per block
#define CHPC 8                           // channels per chunk
#define LDS_ROWS (TILE_ROWS + KK - 1)    // 14
#define LDS_PITCH 72                     // x col c -> lds col c+4
#define CH_STRIDE (LDS_ROWS * LDS_PITCH) // 1008 words per channel plane
#define NQUADS (LDS_ROWS * (LDS_PITCH / 4))  // 252 quad slots per plane
#define BUF_WORDS (CHPC * CH_STRIDE)     // 8064 words = 32256 B per buffer

__global__ __launch_bounds__(256)
__attribute__((amdgpu_waves_per_eu(2, 2)))
void involution_kernel(const float* __restrict__ x,
                       const float* __restrict__ weight,
                       float* __restrict__ out) {
    const int tid = threadIdx.x;
    const int tx = tid & 31;          // wo0 = 2*tx
    const int ty = (tid >> 5) & 7;    // row within tile
    const int bx = blockIdx.x;        // 0..15
    const int tile = bx >> 1;
    const int cs = bx & 1;
    const int g = blockIdx.y;
    const int b = blockIdx.z;

    const int wo0 = tx << 1;
    const int hbase = tile * TILE_ROWS;
    const int ho = hbase + ty;

    __shared__ float xs[2 * BUF_WORDS];   // 64512 B

    // per-pixel weight base: taps at +t*HW, float2 covers wo0,wo0+1
    const float* wq = weight + ((size_t)(b * GG + g) * (KK * KK)) * HW
                    + ho * WW + wo0;

    // staging geometry: LDS word = tid*4 (contiguous in tid => DMA-compatible)
    const int sr = tid / 18;              // 0..13 (tid < 252)
    const int sq = tid - sr * 18;         // 0..17
    const int xrow = hbase + sr - PAD;
    const int xcol = sq * 4 - 4;          // -4..64, quad aligned
    const bool inb = ((unsigned)xrow < HH) && ((unsigned)xcol < WW);
    const bool sval = (tid < NQUADS) && inb;
    const int soff = xrow * WW + xcol;
    const int ldsoff = tid * 4;           // == sr*LDS_PITCH + sq*4
    const int wbase = (tid >> 6) << 8;    // wave's word offset within a plane

    const size_t cbase = (size_t)(b * CC + g * CPG + cs * (NCHUNK * CHPC)) * HW;
    const float* xg = x + cbase;
    float* og = out + cbase + ho * WW + wo0;

    // ---- zero pad slots once (both buffers); DMA never writes them ----
    if (tid < NQUADS && !inb) {
        const float4 z = make_float4(0.f, 0.f, 0.f, 0.f);
#pragma unroll
        for (int ch = 0; ch < CHPC; ++ch) {
            *(float4*)&xs[ch * CH_STRIDE + ldsoff] = z;
            *(float4*)&xs[BUF_WORDS + ch * CH_STRIDE + ldsoff] = z;
        }
    }

    // DMA one chunk's 8 planes into buffer BSEL (exec-masked; LDS dest is
    // wave-uniform base + lane*16B, which matches the tid*16B layout).
#define STAGE(CCI, BSEL)                                                     \
    if (sval) {                                                              \
        const float* gsrc = xg + (size_t)(CCI) * CHPC * HW + soff;           \
        _Pragma("unroll")                                                    \
        for (int ch = 0; ch < CHPC; ++ch)                                    \
            __builtin_amdgcn_global_load_lds(                                \
                (const __attribute__((address_space(1))) void*)(gsrc + ch * HW), \
                (__attribute__((address_space(3))) void*)                    \
                    (&xs[(BSEL) * BUF_WORDS + ch * CH_STRIDE + wbase]),      \
                16, 0, 0);                                                   \
    }

    // ---- prologue: kh=0 taps + chunk 0 staging ----
    float2 wka[KK], wkb[KK];
#pragma unroll
    for (int j = 0; j < KK; ++j)
        wka[j] = *(const float2*)(wq + (size_t)j * HW);

    STAGE(0, 0)

    asm volatile("s_waitcnt vmcnt(0) lgkmcnt(0)" ::: "memory");
    __builtin_amdgcn_s_barrier();

#pragma unroll 1
    for (int cc = 0; cc < NCHUNK; ++cc) {
        asm volatile("" ::: "memory");   // keep the 49 weight loads in-loop
        const float* xb = &xs[(cc & 1) * BUF_WORDS];

        float acc0[CHPC], acc1[CHPC];
#pragma unroll
        for (int ch = 0; ch < CHPC; ++ch) { acc0[ch] = 0.f; acc1[ch] = 0.f; }

#define KH_STEP(KH, WCUR, WNXT, NKH)                                        \
        {                                                                   \
            _Pragma("unroll")                                               \
            for (int j = 0; j < KK; ++j)                                    \
                WNXT[j] = *(const float2*)(wq + (size_t)((NKH) * KK + j) * HW); \
            _Pragma("unroll")                                               \
            for (int ch = 0; ch < CHPC; ++ch) {                             \
                const float* row = xb + ch * CH_STRIDE + (ty + (KH)) * LDS_PITCH + wo0; \
                const float2 p0 = *(const float2*)(row + 0);                \
                const float2 p1 = *(const float2*)(row + 2);                \
                const float2 p2 = *(const float2*)(row + 4);                \
                const float2 p3 = *(const float2*)(row + 6);                \
                const float2 p4 = *(const float2*)(row + 8);                \
                const float f1 = p0.y, f2 = p1.x, f3 = p1.y, f4 = p2.x;     \
                const float f5 = p2.y, f6 = p3.x, f7 = p3.y, f8 = p4.x;     \
                float a0 = acc0[ch], a1 = acc1[ch];                         \
                a0 = fmaf(f1, WCUR[0].x, a0);  a1 = fmaf(f2, WCUR[0].y, a1); \
                a0 = fmaf(f2, WCUR[1].x, a0);  a1 = fmaf(f3, WCUR[1].y, a1); \
                a0 = fmaf(f3, WCUR[2].x, a0);  a1 = fmaf(f4, WCUR[2].y, a1); \
                a0 = fmaf(f4, WCUR[3].x, a0);  a1 = fmaf(f5, WCUR[3].y, a1); \
                a0 = fmaf(f5, WCUR[4].x, a0);  a1 = fmaf(f6, WCUR[4].y, a1); \
                a0 = fmaf(f6, WCUR[5].x, a0);  a1 = fmaf(f7, WCUR[5].y, a1); \
                a0 = fmaf(f7, WCUR[6].x, a0);  a1 = fmaf(f8, WCUR[6].y, a1); \
                acc0[ch] = a0; acc1[ch] = a1;                               \
            }                                                               \
        }

        KH_STEP(0, wka, wkb, 1)
        KH_STEP(1, wkb, wka, 2)
        KH_STEP(2, wka, wkb, 3)

        // issue next chunk's DMA here: retired by kh=4/5's FIFO weight waits,
        // i.e. before this chunk's end barrier -> readers are safe.
        if (cc + 1 < NCHUNK) STAGE(cc + 1, (cc + 1) & 1)

        KH_STEP(3, wkb, wka, 4)
        KH_STEP(4, wka, wkb, 5)
        KH_STEP(5, wkb, wka, 6)
        KH_STEP(6, wka, wkb, 0)   // prefetch kh=0 taps for the next chunk
#undef KH_STEP

        // rotate so next chunk's kh=0 computes from wka
#pragma unroll
        for (int j = 0; j < KK; ++j) wka[j] = wkb[j];

        // ---- store 8 channels x 2 pixels ----
#pragma unroll
        for (int ch = 0; ch < CHPC; ++ch) {
            *(float2*)(og + (size_t)(cc * CHPC + ch) * HW)
                = make_float2(acc0[ch], acc1[ch]);
        }

        // all waves' reads of buf[cc&1] done AND their DMA for chunk cc+1
        // retired (FIFO) before anyone proceeds to overwrite / read ahead.
        __builtin_amdgcn_s_barrier();
    }
}

extern "C" void kernel_launch(void* const* d_in, const int* in_sizes, int n_in,
                              void* d_out, int out_size, void* d_ws, size_t ws_size,
                              hipStream_t stream) {
    const float* x = (const float*)d_in[0];
    const float* w = (const float*)d_in[1];
    float* out = (float*)d_out;

    dim3 grid((HH / TILE_ROWS) * CSPLIT, GG, BB);   // (16, 8, 8) = 1024 blocks
    dim3 block(256);
    involution_kernel<<<grid, block, 0, stream>>>(x, w, out);
}

// Round 4
// 187.187 us; speedup vs baseline: 2.9353x; 2.9353x over previous
//
#include <hip/hip_runtime.h>

// Involution: out[b, g*64+c, ho, wo] = sum_{kh,kw} xp[b, g*64+c, ho+kh, wo+kw] * W[b,g,kh,kw,ho,wo]
// B=8, C=512, G=8, cpg=64, H=W=Ho=Wo=64, K=7, PAD=3. fp32.
//
// R8: revert to the R4 structure (102us, VGPR 64, zero spill) and fix the
// thing its counters indict: weight-panel L2 locality.
// R4 was latency-bound on the per-kh weight loads (VALUBusy 19%); the 803KB
// weight panel of a (b,g) was consumed by blocks sprayed across all 8 XCDs,
// so it was never L2-resident and every kh paid L3/HBM latency.
//   - CSPLIT=8 (NCHUNK=1): 64 blocks per (b,g); per-XCD resident window
//     (~96 blocks) now spans ~1.5 panels (2.7MB < 4MB L2).
//   - bijective XCD swizzle: f -> xcd=f&7, k=f>>3, bg=(k>>6)*8+xcd, sub=k&63.
//     All 64 blocks of a (b,g) land on ONE XCD, consecutive in dispatch.
//   - sched_barrier(0) per kh pins R4's serial load/compute schedule so the
//     now-straight-line code can't hoist all 49 weight loads (the R1-R3/R5
//     98-live-reg spill mode). No other change: register staging, plain
//     __syncthreads, single-buffered weights, launch_bounds(256,4).
// R5/R6/R7 lessons: any added live state or manual vmcnt structure on this
// kernel spills or serializes; pipeline via placement, not registers.

#define BB 8
#define CC 512
#define GG 8
#define CPG 64
#define HH 64
#define WW 64
#define HW (HH * WW)
#define KK 7
#define PAD 3

#define TILE_ROWS 8
#define CSPLIT 8
#define CHPC 8                           // channels per block
#define LDS_ROWS (TILE_ROWS + KK - 1)    // 14
#define LDS_PITCH 72                     // x col c -> lds col c+4
#define CH_STRIDE (LDS_ROWS * LDS_PITCH) // 1008 words per channel plane
#define NQUADS (LDS_ROWS * (LDS_PITCH / 4))  // 252 quad slots per plane

__global__ __launch_bounds__(256, 4)
void involution_kernel(const float* __restrict__ x,
                       const float* __restrict__ weight,
                       float* __restrict__ out) {
    const int tid = threadIdx.x;
    const int tx = tid & 31;          // wo0 = 2*tx
    const int ty = tid >> 5;          // row within tile

    // ---- XCD-locality decode: all 64 sub-blocks of a (b,g) on one XCD ----
    const int f = blockIdx.x;         // 0..4095
    const int xcd = f & 7;
    const int k = f >> 3;             // 0..511
    const int bg = ((k >> 6) << 3) + xcd;   // 0..63, bijective
    const int sub = k & 63;           // 0..63
    const int b = bg >> 3;
    const int g = bg & 7;
    const int tile = sub >> 3;        // 0..7
    const int cs = sub & 7;           // 0..7

    const int wo0 = tx << 1;
    const int hbase = tile * TILE_ROWS;
    const int ho = hbase + ty;

    __shared__ float xs[CHPC * CH_STRIDE];   // 32256 B

    // per-pixel weight base: taps at +t*HW, float2 covers wo0,wo0+1
    const float* wq = weight + ((size_t)(b * GG + g) * (KK * KK)) * HW
                    + ho * WW + wo0;

    // staging geometry
    const int sr = tid / 18;              // 0..13 (tid < 252)
    const int sq = tid - sr * 18;         // 0..17
    const int xrow = hbase + sr - PAD;
    const int xcol = sq * 4 - 4;          // -4..64, quad aligned
    const bool sval = (tid < NQUADS)
                   && ((unsigned)xrow < HH) && ((unsigned)xcol < WW);
    const int soff = xrow * WW + xcol;
    const int ldsoff = sr * LDS_PITCH + sq * 4;

    const size_t cbase = (size_t)(b * CC + g * CPG + cs * CHPC) * HW;
    const float* xg = x + cbase;
    float* og = out + cbase + ho * WW + wo0;

    // ---- stage 8 channel planes (register pass-through, dead after write) ----
    float4 q[CHPC];
#pragma unroll
    for (int ch = 0; ch < CHPC; ++ch) {
        float4 v = make_float4(0.f, 0.f, 0.f, 0.f);
        if (sval)
            v = *(const float4*)(xg + (size_t)ch * HW + soff);
        q[ch] = v;
    }
    if (tid < NQUADS) {
#pragma unroll
        for (int ch = 0; ch < CHPC; ++ch)
            *(float4*)(&xs[ch * CH_STRIDE + ldsoff]) = q[ch];
    }
    __syncthreads();                 // planes visible

    // ---- compute: kh outer (7 float2 weights live), ch inner ----
    float acc0[CHPC], acc1[CHPC];
#pragma unroll
    for (int ch = 0; ch < CHPC; ++ch) { acc0[ch] = 0.f; acc1[ch] = 0.f; }

#pragma unroll
    for (int kh = 0; kh < KK; ++kh) {
        __builtin_amdgcn_sched_barrier(0);   // keep loads in their kh step
        float2 wk[KK];
#pragma unroll
        for (int j = 0; j < KK; ++j)
            wk[j] = *(const float2*)(wq + (size_t)(kh * KK + j) * HW);

#pragma unroll
        for (int ch = 0; ch < CHPC; ++ch) {
            const float* row = &xs[ch * CH_STRIDE + (ty + kh) * LDS_PITCH + wo0];
            const float2 p0 = *(const float2*)(row + 0);
            const float2 p1 = *(const float2*)(row + 2);
            const float2 p2 = *(const float2*)(row + 4);
            const float2 p3 = *(const float2*)(row + 6);
            const float2 p4 = *(const float2*)(row + 8);
            const float f1 = p0.y, f2 = p1.x, f3 = p1.y, f4 = p2.x;
            const float f5 = p2.y, f6 = p3.x, f7 = p3.y, f8 = p4.x;
            float a0 = acc0[ch], a1 = acc1[ch];
            a0 = fmaf(f1, wk[0].x, a0);  a1 = fmaf(f2, wk[0].y, a1);
            a0 = fmaf(f2, wk[1].x, a0);  a1 = fmaf(f3, wk[1].y, a1);
            a0 = fmaf(f3, wk[2].x, a0);  a1 = fmaf(f4, wk[2].y, a1);
            a0 = fmaf(f4, wk[3].x, a0);  a1 = fmaf(f5, wk[3].y, a1);
            a0 = fmaf(f5, wk[4].x, a0);  a1 = fmaf(f6, wk[4].y, a1);
            a0 = fmaf(f6, wk[5].x, a0);  a1 = fmaf(f7, wk[5].y, a1);
            a0 = fmaf(f7, wk[6].x, a0);  a1 = fmaf(f8, wk[6].y, a1);
            acc0[ch] = a0; acc1[ch] = a1;
        }
    }

    // ---- store 8 channels x 2 pixels ----
#pragma unroll
    for (int ch = 0; ch < CHPC; ++ch) {
        *(float2*)(og + (size_t)ch * HW)
            = make_float2(acc0[ch], acc1[ch]);
    }
}

extern "C" void kernel_launch(void* const* d_in, const int* in_sizes, int n_in,
                              void* d_out, int out_size, void* d_ws, size_t ws_size,
                              hipStream_t stream) {
    const float* x = (const float*)d_in[0];
    const float* w = (const float*)d_in[1];
    float* out = (float*)d_out;

    dim3 grid((HH / TILE_ROWS) * CSPLIT * GG * BB);   // 4096 blocks, 1D for swizzle
    dim3 block(256);
    involution_kernel<<<grid, block, 0, stream>>>(x, w, out);
}